// Round 4
// baseline (177.227 us; speedup 1.0000x reference)
//
#include <hip/hip_runtime.h>
#include <math.h>

// Problem constants (B, C, H, W) = (32, 10, 192, 320), fp32.
constexpr int B_ = 32, C_ = 10, H_ = 192, W_ = 320;
constexpr int HW_  = H_ * W_;        // 61440 (512 | HW_ -> no b-crossing per block)
constexpr int CHW_ = C_ * HW_;       // 614400
constexpr int NPTS = B_ * HW_;       // 1966080 spatial points
constexpr int PPT  = 4;              // points per thread (float4 per channel)
constexpr int TPB  = 128;            // 2 waves/block
constexpr int NTHR = NPTS / PPT;     // 491520 threads
constexpr int NBLK = NTHR / TPB;     // 3840 blocks, exact cover

// Partial-sum slots, ws[slot * NBLK + blk]. Final weights folded per-thread:
// 0: nv  1: num_pos
// 2: sum pos*(g0-r0)^2*log(safe+EPS)            (pos_term = -this)
// 3: sum neg*r0^2*log(1+EPS-safe)*(1-g0)^4      (neg_term = -this)
// 4: P  = 0.5*s_pos + 0.5*s_const + 0.1*s_h     (-> P/nv)
// 5: V1 = 0.05*s_len1 + 0.5*s_trig1             (-> V1/nv)
// 6: V2 = 0.05*s_len2 + 0.5*s_trig2             (-> V2/nv)
// loss = focal + (P + min(V1,V2)) / nv
#define NACC 7

typedef float f32x4 __attribute__((ext_vector_type(4)));

__device__ __forceinline__ float sl1f(float d) {
    float ad = fabsf(d);
    return ad < 1.0f ? 0.5f * d * d : ad - 0.5f;
}

// Round-7 evidence: LDS staging (R3) materialized 120KB/CU in flight and
// time did NOT move (59.5us, 4.3 B/cyc/CU) -- but occupancy fell to 12%
// (3 blocks/CU, lockstep issue->drain->compute phases, memory idle during
// compute). Every round so far had EITHER deep MLP OR high occupancy.
// This round: both. Registers-only epoch: 20 float4 loads tied by ONE
// volatile asm (single asm = no inter-load ordering, unlike R1's
// per-channel asms which mandated serialization). VGPR ~110 -> 4 waves/SIMD
// -> 16 waves/CU x 20KB in flight, waves naturally staggered across
// 8 blocks/CU. Discriminates phase-serialization (T-B -> 30-45us) from a
// hard per-CU read-path ceiling (T-A -> unchanged -> roofline).
__global__ __launch_bounds__(TPB) void loss_main(
    const float* __restrict__ re, const float* __restrict__ gt,
    float* __restrict__ ws)
{
    const int tid = blockIdx.x * TPB + threadIdx.x;
    const int p = tid * PPT;
    const int b = p / HW_;           // no b-crossing (PPT*TPB=512 divides HW_)
    const int s = p - b * HW_;
    const float* rp = re + (size_t)b * CHW_ + s;
    const float* gp = gt + (size_t)b * CHW_ + s;

    // One load epoch: 20 independent coalesced dwordx4 loads.
    f32x4 R[10], G[10];
#pragma unroll
    for (int c = 0; c < 10; ++c) {
        R[c] = *(const f32x4*)(rp + c * HW_);
        G[c] = *(const f32x4*)(gp + c * HW_);
    }
    // Single asm ties all 20 results: all 80 floats live HERE, loads issue
    // back-to-back before one wait; no ordering imposed among the loads.
    asm volatile(""
        : "+v"(R[0]), "+v"(R[1]), "+v"(R[2]), "+v"(R[3]), "+v"(R[4]),
          "+v"(R[5]), "+v"(R[6]), "+v"(R[7]), "+v"(R[8]), "+v"(R[9]),
          "+v"(G[0]), "+v"(G[1]), "+v"(G[2]), "+v"(G[3]), "+v"(G[4]),
          "+v"(G[5]), "+v"(G[6]), "+v"(G[7]), "+v"(G[8]), "+v"(G[9]));

    float acc[NACC];
#pragma unroll
    for (int i = 0; i < NACC; ++i) acc[i] = 0.0f;

#pragma unroll
    for (int j = 0; j < PPT; ++j) {
        const float g = G[0][j], r = R[0][j];
        const float m = (g == 1.0f) ? 1.0f : 0.0f;
        acc[0] += m;
        const float pos = (g >= 0.1f) ? 1.0f : 0.0f;
        const float neg = ((g >= 0.0f) && (g < 0.1f)) ? 1.0f : 0.0f;
        acc[1] += pos;
        const float safe = fminf(fmaxf(r, 1e-6f), 1.0f - 1e-6f);
        // pos and neg mutually exclusive -> one logf with selected argument.
        const float larg = (pos != 0.0f) ? (safe + 6e-8f)
                                         : (1.0f + 6e-8f - safe);
        const float lg = logf(larg);
        const float d0 = g - r;
        acc[2] += pos * (d0 * d0) * lg;
        const float omg = 1.0f - g;
        const float omg2 = omg * omg;
        acc[3] += neg * (r * r) * (omg2 * omg2) * lg;

        const float r1 = R[1][j], r2 = R[2][j], r3 = R[3][j], r4v = R[4][j];
        const float r5 = R[5][j], r6 = R[6][j], r7 = R[7][j], r8 = R[8][j],
                    r9 = R[9][j];
        const float g1 = G[1][j], g2 = G[2][j], g3 = G[3][j], g4v = G[4][j];
        const float g5 = G[5][j], g6 = G[6][j], g7 = G[7][j], g8 = G[8][j],
                    g9 = G[9][j];

        // P: pos(0.5) + const(0.5) + height(0.1), all later /nv
        const float sp = sl1f(r1 - g1) + sl1f(r2 - g2);
        const float c1 = 1.0f - r5 * r5 - r4v * r4v;
        const float c2 = 1.0f - r8 * r8 - r7 * r7;
        const float sc = c1 * c1 + c2 * c2;
        const float sh = sl1f(r9 - g9);
        acc[4] += m * (0.5f * sp + 0.5f * sc + 0.1f * sh);

        // V1: 0.05*len1 + 0.5*trig1
        const float d44 = r4v - g4v, d77 = r7 - g7;
        const float d55 = r5 - g5,  d88 = r8 - g8;
        const float t1 = d44 * d44 + d77 * d77 + d55 * d55 + d88 * d88;
        const float l1 = sl1f(r3 - g3) + sl1f(r6 - g6);
        acc[5] += m * (0.05f * l1 + 0.5f * t1);

        // V2: 0.05*len2 + 0.5*trig2
        const float d47 = r4v - g7, d74 = r7 - g4v;
        const float d58 = r5 - g8,  d85 = r8 - g5;
        const float t2 = d47 * d47 + d74 * d74 + d58 * d58 + d85 * d85;
        const float l2 = sl1f(r3 - g6) + sl1f(r6 - g3);
        acc[6] += m * (0.05f * l2 + 0.5f * t2);
    }

    // block reduction: wave shuffle (64 lanes) -> LDS (2 waves) -> plain store
    __shared__ float smem[NACC][2];
    const int lane = threadIdx.x & 63;
    const int wid  = threadIdx.x >> 6;
#pragma unroll
    for (int i = 0; i < NACC; ++i) {
        float v = acc[i];
#pragma unroll
        for (int off = 32; off > 0; off >>= 1) v += __shfl_down(v, off, 64);
        if (lane == 0) smem[i][wid] = v;
    }
    __syncthreads();
    if (threadIdx.x < NACC) {
        const int i = threadIdx.x;
        ws[i * NBLK + blockIdx.x] = smem[i][0] + smem[i][1];
    }
}

// One block, 960 threads: 960*4 = 3840 exact -> guard-free, all 28 loads per
// thread independent, single load epoch.
__global__ __launch_bounds__(960) void loss_reduce(
    const float* __restrict__ ws, float* __restrict__ out)
{
    float acc[NACC];
#pragma unroll
    for (int i = 0; i < NACC; ++i) acc[i] = 0.0f;

#pragma unroll
    for (int k = 0; k < 4; ++k) {
        const int idx = threadIdx.x + k * 960;
#pragma unroll
        for (int i = 0; i < NACC; ++i)
            acc[i] += ws[i * NBLK + idx];
    }

    __shared__ float smem[NACC][15];
    const int lane = threadIdx.x & 63;
    const int wid  = threadIdx.x >> 6;
#pragma unroll
    for (int i = 0; i < NACC; ++i) {
        float v = acc[i];
#pragma unroll
        for (int off = 32; off > 0; off >>= 1) v += __shfl_down(v, off, 64);
        if (lane == 0) smem[i][wid] = v;
    }
    __syncthreads();

    if (threadIdx.x == 0) {
        float slot[NACC];
#pragma unroll
        for (int i = 0; i < NACC; ++i) {
            float v = 0.0f;
#pragma unroll
            for (int w = 0; w < 15; ++w) v += smem[i][w];
            slot[i] = v;
        }
        const float nv    = slot[0];
        const float npos  = slot[1];
        const float pterm = -slot[2];
        const float nterm = -slot[3];
        const float focal = (npos == 0.0f) ? nterm : (pterm + nterm) / npos;
        out[0] = focal + (slot[4] + fminf(slot[5], slot[6])) / nv;
    }
}

extern "C" void kernel_launch(void* const* d_in, const int* in_sizes, int n_in,
                              void* d_out, int out_size, void* d_ws, size_t ws_size,
                              hipStream_t stream)
{
    const float* re = (const float*)d_in[0];
    const float* gt = (const float*)d_in[1];
    float* ws  = (float*)d_ws;
    float* out = (float*)d_out;

    loss_main<<<NBLK, TPB, 0, stream>>>(re, gt, ws);
    loss_reduce<<<1, 960, 0, stream>>>(ws, out);
}